// Round 12
// baseline (322.105 us; speedup 1.0000x reference)
//
#include <hip/hip_runtime.h>

#define HID 128
#define BK_SHIFT 9            // 512 nodes per bucket
#define BK_NODES 512
#define BKCAP 10240           // padded slots per bucket (mean 8192, sigma ~90)
#define EDGES_PER_BLKA 8192

typedef _Float16 half_t;
typedef __attribute__((ext_vector_type(8))) _Float16 half8;
typedef __attribute__((ext_vector_type(4))) _Float16 half4;
typedef __attribute__((ext_vector_type(4))) float f32x4;

// ---------------------------------------------------------------- init: bucket cursors to fixed bases + zero mean
__global__ __launch_bounds__(256) void k_init(int* __restrict__ bcur,
                                              float* __restrict__ outmean) {
  int i = threadIdx.x;
  bcur[i] = i * BKCAP;
  if (i < HID) outmean[i] = 0.f;
}

// ---------------------------------------------------------------- pack 5 W [128][128] f32 -> MFMA B-fragment fp16
__global__ __launch_bounds__(256) void k_packW5(const float* __restrict__ w0,
                                                const float* __restrict__ w1,
                                                const float* __restrict__ w2,
                                                const float* __restrict__ w3,
                                                const float* __restrict__ w4,
                                                half_t* __restrict__ o0,
                                                half_t* __restrict__ o1,
                                                half_t* __restrict__ o2,
                                                half_t* __restrict__ o3,
                                                half_t* __restrict__ o4) {
  int m = blockIdx.x >> 3;
  const float* W = (m == 0) ? w0 : (m == 1) ? w1 : (m == 2) ? w2 : (m == 3) ? w3 : w4;
  half_t* out = (m == 0) ? o0 : (m == 1) ? o1 : (m == 2) ? o2 : (m == 3) ? o3 : o4;
  int tid = (blockIdx.x & 7) * 256 + threadIdx.x;   // 0..2047
  int lane = tid & 63;
  int frag = tid >> 6;                              // 0..31
  int ks = frag >> 3, nt = frag & 7;
  int k0 = ks * 32 + ((lane >> 4) << 3);
  int col = nt * 16 + (lane & 15);
  half8 v;
#pragma unroll
  for (int i = 0; i < 8; ++i) v[i] = (half_t)W[(k0 + i) * HID + col];
  *(half8*)&out[(size_t)tid * 8] = v;
}

// ---------------------------------------------------------------- embed: h0 = relu([z,pos] @ W_in + b_in) -> fp16 table
__global__ __launch_bounds__(256) void k_embed(const float* __restrict__ pos,
                                               const int* __restrict__ an,
                                               const float* __restrict__ Win,
                                               const float* __restrict__ bin,
                                               half_t* __restrict__ h, int n) {
  int t = blockIdx.x * 256 + threadIdx.x;
  int i = t >> 5, cg = t & 31;
  if (i >= n) return;
  int j0 = cg << 2;
  float z  = (float)an[i] / 10.0f;
  float px = pos[3 * i + 0], py = pos[3 * i + 1], pz = pos[3 * i + 2];
  float4 w0 = *(const float4*)&Win[0 * HID + j0];
  float4 w1 = *(const float4*)&Win[1 * HID + j0];
  float4 w2 = *(const float4*)&Win[2 * HID + j0];
  float4 w3 = *(const float4*)&Win[3 * HID + j0];
  float4 b  = *(const float4*)&bin[j0];
  float4 o;
  o.x = fmaxf(fmaf(z, w0.x, fmaf(px, w1.x, fmaf(py, w2.x, fmaf(pz, w3.x, b.x)))), 0.f);
  o.y = fmaxf(fmaf(z, w0.y, fmaf(px, w1.y, fmaf(py, w2.y, fmaf(pz, w3.y, b.y)))), 0.f);
  o.z = fmaxf(fmaf(z, w0.z, fmaf(px, w1.z, fmaf(py, w2.z, fmaf(pz, w3.z, b.z)))), 0.f);
  o.w = fmaxf(fmaf(z, w0.w, fmaf(px, w1.w, fmaf(py, w2.w, fmaf(pz, w3.w, b.w)))), 0.f);
  half4 ph;
  ph.x = (half_t)o.x; ph.y = (half_t)o.y; ph.z = (half_t)o.z; ph.w = (half_t)o.w;
  *(half4*)&h[(size_t)i * HID + j0] = ph;
}

// ---------------------------------------------------------------- pass A: bin edges into padded dst-buckets
__global__ __launch_bounds__(1024) void k_bucketA(const int* __restrict__ src,
                                                  const int* __restrict__ dst,
                                                  int* __restrict__ bcur,
                                                  unsigned* __restrict__ ebuf,
                                                  int e) {
  __shared__ int hist[256];
  __shared__ int resv[256];
  int t = threadIdx.x;
  if (t < 256) hist[t] = 0;
  __syncthreads();
  int e0 = blockIdx.x * EDGES_PER_BLKA;
  int myb[8], myr[8];
  unsigned mypk[8];
#pragma unroll
  for (int i = 0; i < 8; ++i) {
    int idx = e0 + i * 1024 + t;
    if (idx < e) {
      int d = dst[idx];
      int s = src[idx];
      int b = d >> BK_SHIFT;
      myb[i] = b;
      myr[i] = atomicAdd(&hist[b], 1);
      mypk[i] = ((unsigned)s << BK_SHIFT) | (unsigned)(d & (BK_NODES - 1));
    } else {
      myb[i] = -1;
    }
  }
  __syncthreads();
  if (t < 256) resv[t] = (hist[t] > 0) ? atomicAdd(&bcur[t], hist[t]) : 0;
  __syncthreads();
#pragma unroll
  for (int i = 0; i < 8; ++i) {
    if (myb[i] >= 0) ebuf[resv[myb[i]] + myr[i]] = mypk[i];
  }
}

// ---------------------------------------------------------------- pass B: per bucket: LDS node-hist -> scan -> offs/offsE + csr
__global__ __launch_bounds__(256) void k_bucketB(const unsigned* __restrict__ ebuf,
                                                 const int* __restrict__ bkend,
                                                 int* __restrict__ offs,
                                                 int* __restrict__ offsE,
                                                 int* __restrict__ csr, int n) {
  __shared__ int hist[BK_NODES];
  __shared__ int pscan[256];
  int b = blockIdx.x;
  int n0 = b << BK_SHIFT;
  int t = threadIdx.x;
  int ebeg = b * BKCAP, eend = bkend[b];
  hist[t] = 0; hist[t + 256] = 0;
  __syncthreads();
  for (int idx = ebeg + t; idx < eend; idx += 256) {
    atomicAdd(&hist[ebuf[idx] & (BK_NODES - 1)], 1);
  }
  __syncthreads();
  int h0 = hist[2 * t], h1 = hist[2 * t + 1];
  int ps = h0 + h1;
  pscan[t] = ps;
  __syncthreads();
  for (int d = 1; d < 256; d <<= 1) {
    int u = (t >= d) ? pscan[t - d] : 0;
    __syncthreads();
    pscan[t] += u;
    __syncthreads();
  }
  int base0 = ebeg + (pscan[t] - ps);   // exclusive
  int g0 = n0 + 2 * t, g1 = g0 + 1;
  if (g0 < n) { offs[g0] = base0;      offsE[g0] = base0 + h0; }
  if (g1 < n) { offs[g1] = base0 + h0; offsE[g1] = base0 + h0 + h1; }
  __syncthreads();
  hist[2 * t] = base0;
  hist[2 * t + 1] = base0 + h0;
  __syncthreads();
  for (int idx = ebeg + t; idx < eend; idx += 256) {
    unsigned pk = ebuf[idx];
    int dl = pk & (BK_NODES - 1);
    int slot = atomicAdd(&hist[dl], 1);
    csr[slot] = (int)(pk >> BK_SHIFT);
  }
}

// ---------------------------------------------------------------- fused SAGE conv: aggregate -> LDS -> MFMA
// out = relu(agg(h) @ Wl + h @ Wr + b), fp16 in/out.
// Phase 1: 16 lanes/node, masked 8-deep gather (8 independent 16B loads in flight).
// Phase 2: 16x16x32 MFMA, A(agg) from LDS, A(self) from global.
__global__ __launch_bounds__(256) void k_conv_fused(const half_t* __restrict__ h,
                                                    const int* __restrict__ csr,
                                                    const int* __restrict__ offs,
                                                    const int* __restrict__ offsE,
                                                    const half_t* __restrict__ wl,
                                                    const half_t* __restrict__ wr,
                                                    const float* __restrict__ bias,
                                                    half_t* __restrict__ out, int n) {
  __shared__ half_t Ds[64][136];   // 272B row stride: 16B-aligned, 2-way max bank aliasing
  int tid = threadIdx.x;
  int lane = tid & 63;
  int wid = tid >> 6;
  int row0 = blockIdx.x * 64;
  int gl = lane & 15;              // 16B column slot
  int grp = lane >> 4;             // node slot within a round
  size_t coff = (size_t)gl * 8;

  // ---- phase 1: aggregate 16 nodes per wave (4 rounds x 4 nodes)
  for (int rnd = 0; rnd < 4; ++rnd) {
    int lrow = wid * 16 + rnd * 4 + grp;
    int nd = row0 + lrow;
    int beg = 0, end = 0;
    if (nd < n) { beg = offs[nd]; end = offsE[nd]; }
    float acc[8];
#pragma unroll
    for (int q = 0; q < 8; ++q) acc[q] = 0.f;
    for (int e = beg; e < end; e += 8) {
      int last = end - 1;
      int s0 = csr[(e + 0) <= last ? (e + 0) : last];
      int s1 = csr[(e + 1) <= last ? (e + 1) : last];
      int s2 = csr[(e + 2) <= last ? (e + 2) : last];
      int s3 = csr[(e + 3) <= last ? (e + 3) : last];
      int s4 = csr[(e + 4) <= last ? (e + 4) : last];
      int s5 = csr[(e + 5) <= last ? (e + 5) : last];
      int s6 = csr[(e + 6) <= last ? (e + 6) : last];
      int s7 = csr[(e + 7) <= last ? (e + 7) : last];
      half8 v0 = *(const half8*)&h[(size_t)s0 * HID + coff];
      half8 v1 = *(const half8*)&h[(size_t)s1 * HID + coff];
      half8 v2 = *(const half8*)&h[(size_t)s2 * HID + coff];
      half8 v3 = *(const half8*)&h[(size_t)s3 * HID + coff];
      half8 v4 = *(const half8*)&h[(size_t)s4 * HID + coff];
      half8 v5 = *(const half8*)&h[(size_t)s5 * HID + coff];
      half8 v6 = *(const half8*)&h[(size_t)s6 * HID + coff];
      half8 v7 = *(const half8*)&h[(size_t)s7 * HID + coff];
      int rem = end - e;   // >=1
#pragma unroll
      for (int q = 0; q < 8; ++q) {
        float a = (float)v0[q];
        if (rem > 1) a += (float)v1[q];
        if (rem > 2) a += (float)v2[q];
        if (rem > 3) a += (float)v3[q];
        if (rem > 4) a += (float)v4[q];
        if (rem > 5) a += (float)v5[q];
        if (rem > 6) a += (float)v6[q];
        if (rem > 7) a += (float)v7[q];
        acc[q] += a;
      }
    }
    int c = end - beg;
    float inv = (c > 0) ? 1.0f / (float)c : 0.0f;
    half8 o;
#pragma unroll
    for (int q = 0; q < 8; ++q) o[q] = (half_t)(acc[q] * inv);
    *(half8*)&Ds[lrow][gl * 8] = o;
  }
  __syncthreads();

  // ---- phase 2: MFMA over the 64-row tile
  int lrow16 = wid * 16 + (lane & 15);
  int hrow = row0 + lrow16;
  int hrowc = hrow < n ? hrow : n - 1;
  size_t hbase = (size_t)hrowc * HID + ((lane >> 4) << 3);
  int acol = ((lane >> 4) << 3);
  const half8* WL = (const half8*)wl;
  const half8* WR = (const half8*)wr;
  f32x4 acc2[8];
#pragma unroll
  for (int t2 = 0; t2 < 8; ++t2) acc2[t2] = (f32x4){0.f, 0.f, 0.f, 0.f};
#pragma unroll
  for (int ks = 0; ks < 4; ++ks) {
    half8 aD = *(const half8*)&Ds[lrow16][ks * 32 + acol];
    half8 aH = *(const half8*)&h[hbase + ks * 32];
    int fb = ks * 8;
#pragma unroll
    for (int nt = 0; nt < 8; ++nt) {
      half8 bl = WL[(size_t)(fb + nt) * 64 + lane];
      half8 br = WR[(size_t)(fb + nt) * 64 + lane];
      acc2[nt] = __builtin_amdgcn_mfma_f32_16x16x32_f16(aD, bl, acc2[nt], 0, 0, 0);
      acc2[nt] = __builtin_amdgcn_mfma_f32_16x16x32_f16(aH, br, acc2[nt], 0, 0, 0);
    }
  }
  int rbase = row0 + wid * 16 + ((lane >> 4) << 2);
  int cl = lane & 15;
#pragma unroll
  for (int nt = 0; nt < 8; ++nt) {
    int col = nt * 16 + cl;
    float bv = bias[col];
#pragma unroll
    for (int r = 0; r < 4; ++r) {
      int row = rbase + r;
      if (row < n) {
        float v = fmaxf(acc2[nt][r] + bv, 0.f);
        out[(size_t)row * HID + col] = (half_t)v;
      }
    }
  }
}

// ---------------------------------------------------------------- MFMA single GEMM: ns = h@W + b (f32 out) + block col sums
__global__ __launch_bounds__(256) void k_single_mfma(const half_t* __restrict__ hs,
                                                     const half_t* __restrict__ w,
                                                     const float* __restrict__ bias,
                                                     float* __restrict__ out,
                                                     float* __restrict__ part, int n) {
  __shared__ float colsum[HID];
  int tid = threadIdx.x;
  int lane = tid & 63;
  int wid = tid >> 6;
  if (tid < HID) colsum[tid] = 0.f;
  __syncthreads();
  int row0 = blockIdx.x * 64 + wid * 16;
  bool active = row0 < n;
  f32x4 acc[8];
#pragma unroll
  for (int t = 0; t < 8; ++t) acc[t] = (f32x4){0.f, 0.f, 0.f, 0.f};
  if (active) {
    int arow = row0 + (lane & 15);
    int arowc = arow < n ? arow : n - 1;
    size_t abase = (size_t)arowc * HID + ((lane >> 4) << 3);
    const half8* W8 = (const half8*)w;
#pragma unroll
    for (int ks = 0; ks < 4; ++ks) {
      half8 aH = *(const half8*)&hs[abase + ks * 32];
      int fb = ks * 8;
#pragma unroll
      for (int nt = 0; nt < 8; ++nt) {
        half8 b = W8[(size_t)(fb + nt) * 64 + lane];
        acc[nt] = __builtin_amdgcn_mfma_f32_16x16x32_f16(aH, b, acc[nt], 0, 0, 0);
      }
    }
    int rbase = row0 + ((lane >> 4) << 2);
    int cl = lane & 15;
#pragma unroll
    for (int nt = 0; nt < 8; ++nt) {
      int col = nt * 16 + cl;
      float bv = bias[col];
      float csum = 0.f;
#pragma unroll
      for (int r = 0; r < 4; ++r) {
        int row = rbase + r;
        if (row < n) {
          float v = acc[nt][r] + bv;
          out[(size_t)row * HID + col] = v;
          csum += v;
        }
      }
      atomicAdd(&colsum[col], csum);
    }
  }
  __syncthreads();
  if (tid < HID) part[(size_t)blockIdx.x * HID + tid] = colsum[tid];
}

// ---------------------------------------------------------------- final column reduce
__global__ __launch_bounds__(256) void k_colfinal(const float* __restrict__ part,
                                                  float* __restrict__ outmean,
                                                  int rows, float inv) {
  __shared__ float red[256];
  int t = threadIdx.x;
  int col = t & 127, half = t >> 7;
  int r0 = blockIdx.x * 256;
  float s = 0.f;
  for (int r = half; r < 256; r += 2) {
    int row = r0 + r;
    if (row < rows) s += part[(size_t)row * HID + col];
  }
  red[t] = s;
  __syncthreads();
  if (t < 128) atomicAdd(&outmean[col], (red[t] + red[t + 128]) * inv);
}

// ---------------------------------------------------------------- launch
extern "C" void kernel_launch(void* const* d_in, const int* in_sizes, int n_in,
                              void* d_out, int out_size, void* d_ws, size_t ws_size,
                              hipStream_t stream) {
  const float* pos  = (const float*)d_in[0];
  const int*   an   = (const int*)d_in[1];
  const int*   ei   = (const int*)d_in[2];
  const float* Win  = (const float*)d_in[3];
  const float* bin  = (const float*)d_in[4];
  const float* W1l  = (const float*)d_in[5];
  const float* b1   = (const float*)d_in[6];
  const float* W1r  = (const float*)d_in[7];
  const float* W2l  = (const float*)d_in[8];
  const float* b2   = (const float*)d_in[9];
  const float* W2r  = (const float*)d_in[10];
  const float* Wout = (const float*)d_in[11];
  const float* bout = (const float*)d_in[12];

  int N = in_sizes[0] / 3;
  int E = in_sizes[2] / 2;
  const int* srcl = ei;
  const int* dstl = ei + E;

  float* outmean = (float*)d_out;
  float* ns      = (float*)d_out + HID;

  char* p = (char*)d_ws;
  auto take = [&](size_t bytes) {
    char* q = p;
    p += (bytes + 255) & ~(size_t)255;
    return q;
  };
  int nbuck = (N + BK_NODES - 1) / BK_NODES;       // 196
  half_t*   H0      = (half_t*)take((size_t)N * HID * 2);
  half_t*   H1      = (half_t*)take((size_t)N * HID * 2);
  half_t*   H2      = (half_t*)take((size_t)N * HID * 2);
  int*      offs    = (int*)take((size_t)N * 4);
  int*      offsE   = (int*)take((size_t)N * 4);
  int*      csr     = (int*)take((size_t)nbuck * BKCAP * 4);
  unsigned* ebuf    = (unsigned*)take((size_t)nbuck * BKCAP * 4);
  int*      bcur    = (int*)take((size_t)256 * 4);
  half_t*   pW1l    = (half_t*)take((size_t)16384 * 2);
  half_t*   pW1r    = (half_t*)take((size_t)16384 * 2);
  half_t*   pW2l    = (half_t*)take((size_t)16384 * 2);
  half_t*   pW2r    = (half_t*)take((size_t)16384 * 2);
  half_t*   pWout   = (half_t*)take((size_t)16384 * 2);
  int gSage = (N + 63) / 64;
  float*    colpart = (float*)take((size_t)gSage * HID * 4);

  int gEmbed = (int)(((size_t)N * 32 + 255) / 256);
  int gBktA  = (E + EDGES_PER_BLKA - 1) / EDGES_PER_BLKA;

  k_init<<<1, 256, 0, stream>>>(bcur, outmean);
  k_packW5<<<40, 256, 0, stream>>>(W1l, W1r, W2l, W2r, Wout,
                                   pW1l, pW1r, pW2l, pW2r, pWout);
  k_embed<<<gEmbed, 256, 0, stream>>>(pos, an, Win, bin, H0, N);
  k_bucketA<<<gBktA, 1024, 0, stream>>>(srcl, dstl, bcur, ebuf, E);
  k_bucketB<<<nbuck, 256, 0, stream>>>(ebuf, bcur, offs, offsE, csr, N);

  // conv1 + conv2 (fused aggregate+GEMM)
  k_conv_fused<<<gSage, 256, 0, stream>>>(H0, csr, offs, offsE, pW1l, pW1r, b1, H1, N);
  k_conv_fused<<<gSage, 256, 0, stream>>>(H1, csr, offs, offsE, pW2l, pW2r, b2, H2, N);
  // output projection + column mean
  k_single_mfma<<<gSage, 256, 0, stream>>>(H2, pWout, bout, ns, colpart, N);
  k_colfinal<<<(gSage + 255) / 256, 256, 0, stream>>>(colpart, outmean, gSage, 1.0f / (float)N);
}

// Round 13
// 308.750 us; speedup vs baseline: 1.0433x; 1.0433x over previous
//
#include <hip/hip_runtime.h>

#define HID 128
#define BK_SHIFT 9            // 512 nodes per bucket
#define BK_NODES 512
#define BKCAP 10240           // padded slots per bucket (mean 8192, sigma ~90)
#define EDGES_PER_BLKA 8192

typedef _Float16 half_t;
typedef __attribute__((ext_vector_type(8))) _Float16 half8;
typedef __attribute__((ext_vector_type(4))) _Float16 half4;
typedef __attribute__((ext_vector_type(4))) float f32x4;

// ---------------------------------------------------------------- init: bucket cursors + zero mean + zero rows (idx n)
__global__ __launch_bounds__(256) void k_init(int* __restrict__ bcur,
                                              float* __restrict__ outmean,
                                              half_t* __restrict__ h0z,
                                              half_t* __restrict__ h1z) {
  int i = threadIdx.x;
  bcur[i] = i * BKCAP;
  if (i < HID) outmean[i] = 0.f;
  if (i < HID) h0z[i] = (half_t)0.f;
  else         h1z[i - HID] = (half_t)0.f;
}

// ---------------------------------------------------------------- pack 5 W [128][128] f32 -> MFMA B-fragment fp16
__global__ __launch_bounds__(256) void k_packW5(const float* __restrict__ w0,
                                                const float* __restrict__ w1,
                                                const float* __restrict__ w2,
                                                const float* __restrict__ w3,
                                                const float* __restrict__ w4,
                                                half_t* __restrict__ o0,
                                                half_t* __restrict__ o1,
                                                half_t* __restrict__ o2,
                                                half_t* __restrict__ o3,
                                                half_t* __restrict__ o4) {
  int m = blockIdx.x >> 3;
  const float* W = (m == 0) ? w0 : (m == 1) ? w1 : (m == 2) ? w2 : (m == 3) ? w3 : w4;
  half_t* out = (m == 0) ? o0 : (m == 1) ? o1 : (m == 2) ? o2 : (m == 3) ? o3 : o4;
  int tid = (blockIdx.x & 7) * 256 + threadIdx.x;   // 0..2047
  int lane = tid & 63;
  int frag = tid >> 6;                              // 0..31
  int ks = frag >> 3, nt = frag & 7;
  int k0 = ks * 32 + ((lane >> 4) << 3);
  int col = nt * 16 + (lane & 15);
  half8 v;
#pragma unroll
  for (int i = 0; i < 8; ++i) v[i] = (half_t)W[(k0 + i) * HID + col];
  *(half8*)&out[(size_t)tid * 8] = v;
}

// ---------------------------------------------------------------- embed: h0 = relu([z,pos] @ W_in + b_in) -> fp16 table
__global__ __launch_bounds__(256) void k_embed(const float* __restrict__ pos,
                                               const int* __restrict__ an,
                                               const float* __restrict__ Win,
                                               const float* __restrict__ bin,
                                               half_t* __restrict__ h, int n) {
  int t = blockIdx.x * 256 + threadIdx.x;
  int i = t >> 5, cg = t & 31;
  if (i >= n) return;
  int j0 = cg << 2;
  float z  = (float)an[i] / 10.0f;
  float px = pos[3 * i + 0], py = pos[3 * i + 1], pz = pos[3 * i + 2];
  float4 w0 = *(const float4*)&Win[0 * HID + j0];
  float4 w1 = *(const float4*)&Win[1 * HID + j0];
  float4 w2 = *(const float4*)&Win[2 * HID + j0];
  float4 w3 = *(const float4*)&Win[3 * HID + j0];
  float4 b  = *(const float4*)&bin[j0];
  float4 o;
  o.x = fmaxf(fmaf(z, w0.x, fmaf(px, w1.x, fmaf(py, w2.x, fmaf(pz, w3.x, b.x)))), 0.f);
  o.y = fmaxf(fmaf(z, w0.y, fmaf(px, w1.y, fmaf(py, w2.y, fmaf(pz, w3.y, b.y)))), 0.f);
  o.z = fmaxf(fmaf(z, w0.z, fmaf(px, w1.z, fmaf(py, w2.z, fmaf(pz, w3.z, b.z)))), 0.f);
  o.w = fmaxf(fmaf(z, w0.w, fmaf(px, w1.w, fmaf(py, w2.w, fmaf(pz, w3.w, b.w)))), 0.f);
  half4 ph;
  ph.x = (half_t)o.x; ph.y = (half_t)o.y; ph.z = (half_t)o.z; ph.w = (half_t)o.w;
  *(half4*)&h[(size_t)i * HID + j0] = ph;
}

// ---------------------------------------------------------------- pass A: bin edges into padded dst-buckets
__global__ __launch_bounds__(1024) void k_bucketA(const int* __restrict__ src,
                                                  const int* __restrict__ dst,
                                                  int* __restrict__ bcur,
                                                  unsigned* __restrict__ ebuf,
                                                  int e) {
  __shared__ int hist[256];
  __shared__ int resv[256];
  int t = threadIdx.x;
  if (t < 256) hist[t] = 0;
  __syncthreads();
  int e0 = blockIdx.x * EDGES_PER_BLKA;
  int myb[8], myr[8];
  unsigned mypk[8];
#pragma unroll
  for (int i = 0; i < 8; ++i) {
    int idx = e0 + i * 1024 + t;
    if (idx < e) {
      int d = dst[idx];
      int s = src[idx];
      int b = d >> BK_SHIFT;
      myb[i] = b;
      myr[i] = atomicAdd(&hist[b], 1);
      mypk[i] = ((unsigned)s << BK_SHIFT) | (unsigned)(d & (BK_NODES - 1));
    } else {
      myb[i] = -1;
    }
  }
  __syncthreads();
  if (t < 256) resv[t] = (hist[t] > 0) ? atomicAdd(&bcur[t], hist[t]) : 0;
  __syncthreads();
#pragma unroll
  for (int i = 0; i < 8; ++i) {
    if (myb[i] >= 0) ebuf[resv[myb[i]] + myr[i]] = mypk[i];
  }
}

// ---------------------------------------------------------------- pass B: per bucket: LDS node-hist -> scan -> offs/offsE + csr
__global__ __launch_bounds__(256) void k_bucketB(const unsigned* __restrict__ ebuf,
                                                 const int* __restrict__ bkend,
                                                 int* __restrict__ offs,
                                                 int* __restrict__ offsE,
                                                 int* __restrict__ csr, int n) {
  __shared__ int hist[BK_NODES];
  __shared__ int pscan[256];
  int b = blockIdx.x;
  int n0 = b << BK_SHIFT;
  int t = threadIdx.x;
  int ebeg = b * BKCAP, eend = bkend[b];
  hist[t] = 0; hist[t + 256] = 0;
  __syncthreads();
  for (int idx = ebeg + t; idx < eend; idx += 256) {
    atomicAdd(&hist[ebuf[idx] & (BK_NODES - 1)], 1);
  }
  __syncthreads();
  int h0 = hist[2 * t], h1 = hist[2 * t + 1];
  int ps = h0 + h1;
  pscan[t] = ps;
  __syncthreads();
  for (int d = 1; d < 256; d <<= 1) {
    int u = (t >= d) ? pscan[t - d] : 0;
    __syncthreads();
    pscan[t] += u;
    __syncthreads();
  }
  int base0 = ebeg + (pscan[t] - ps);   // exclusive
  int g0 = n0 + 2 * t, g1 = g0 + 1;
  if (g0 < n) { offs[g0] = base0;      offsE[g0] = base0 + h0; }
  if (g1 < n) { offs[g1] = base0 + h0; offsE[g1] = base0 + h0 + h1; }
  __syncthreads();
  hist[2 * t] = base0;
  hist[2 * t + 1] = base0 + h0;
  __syncthreads();
  for (int idx = ebeg + t; idx < eend; idx += 256) {
    unsigned pk = ebuf[idx];
    int dl = pk & (BK_NODES - 1);
    int slot = atomicAdd(&hist[dl], 1);
    csr[slot] = (int)(pk >> BK_SHIFT);
  }
}

// ---------------------------------------------------------------- mean aggregation: wave = 1 node, 16 lanes/edge-row,
// single masked 32-edge round: 8 independent dwordx4 loads/lane in flight; junk slots -> zero row (idx n)
__global__ __launch_bounds__(256) void k_aggmean_f16(const half_t* __restrict__ h,
                                                     const int* __restrict__ csr,
                                                     const int* __restrict__ offs,
                                                     const int* __restrict__ offsE,
                                                     half_t* __restrict__ out, int n) {
  int w = (blockIdx.x * 256 + threadIdx.x) >> 6;
  int lane = threadIdx.x & 63;
  if (w >= n) return;
  int cs = lane & 15, es = lane >> 4;        // cs: 16B col slot; es: edge slot in [0,4)
  int beg = offs[w], end = offsE[w];
  size_t coff = (size_t)(cs * 8);
  float acc[8];
#pragma unroll
  for (int j = 0; j < 8; ++j) acc[j] = 0.f;
  int last = end - 1;
  for (int e = beg; e < end; e += 32) {
    int i0 = e + es;
    int s[8];
#pragma unroll
    for (int k = 0; k < 8; ++k) {
      int idx = i0 + 4 * k;
      int cidx = idx <= last ? idx : last;   // safe csr read
      int sr = csr[cidx];
      s[k] = (idx <= last) ? sr : n;         // junk -> zero row
    }
    half8 v0 = *(const half8*)&h[(size_t)s[0] * HID + coff];
    half8 v1 = *(const half8*)&h[(size_t)s[1] * HID + coff];
    half8 v2 = *(const half8*)&h[(size_t)s[2] * HID + coff];
    half8 v3 = *(const half8*)&h[(size_t)s[3] * HID + coff];
    half8 v4 = *(const half8*)&h[(size_t)s[4] * HID + coff];
    half8 v5 = *(const half8*)&h[(size_t)s[5] * HID + coff];
    half8 v6 = *(const half8*)&h[(size_t)s[6] * HID + coff];
    half8 v7 = *(const half8*)&h[(size_t)s[7] * HID + coff];
#pragma unroll
    for (int j = 0; j < 8; ++j) {
      float a = ((float)v0[j] + (float)v1[j]) + ((float)v2[j] + (float)v3[j]);
      float b = ((float)v4[j] + (float)v5[j]) + ((float)v6[j] + (float)v7[j]);
      acc[j] += a + b;
    }
  }
  // reduce across the 4 edge slots (stride 16, 32)
#pragma unroll
  for (int j = 0; j < 8; ++j) {
    acc[j] += __shfl_xor(acc[j], 16, 64);
    acc[j] += __shfl_xor(acc[j], 32, 64);
  }
  if (es == 0) {
    int c = end - beg;
    float inv = (c > 0) ? 1.0f / (float)c : 0.0f;
    half8 o;
#pragma unroll
    for (int j = 0; j < 8; ++j) o[j] = (half_t)(acc[j] * inv);
    *(half8*)&out[(size_t)w * HID + coff] = o;
  }
}

// ---------------------------------------------------------------- MFMA SAGE: out = relu(ha@Wl + hs@Wr + b), fp16 in/out
__global__ __launch_bounds__(256) void k_sage_mfma(const half_t* __restrict__ ha,
                                                   const half_t* __restrict__ hs,
                                                   const half_t* __restrict__ wl,
                                                   const half_t* __restrict__ wr,
                                                   const float* __restrict__ bias,
                                                   half_t* __restrict__ out, int n) {
  int lane = threadIdx.x & 63;
  int wid = threadIdx.x >> 6;
  int row0 = blockIdx.x * 64 + wid * 16;
  if (row0 >= n) return;
  int arow = row0 + (lane & 15);
  int arowc = arow < n ? arow : n - 1;   // clamp; rows >= n never stored
  size_t abase = (size_t)arowc * HID + ((lane >> 4) << 3);
  const half8* WL = (const half8*)wl;
  const half8* WR = (const half8*)wr;
  f32x4 acc[8];
#pragma unroll
  for (int t = 0; t < 8; ++t) acc[t] = (f32x4){0.f, 0.f, 0.f, 0.f};
#pragma unroll
  for (int ks = 0; ks < 4; ++ks) {
    half8 aD = *(const half8*)&ha[abase + ks * 32];
    half8 aH = *(const half8*)&hs[abase + ks * 32];
    int fb = ks * 8;
#pragma unroll
    for (int nt = 0; nt < 8; ++nt) {
      half8 bl = WL[(size_t)(fb + nt) * 64 + lane];
      half8 br = WR[(size_t)(fb + nt) * 64 + lane];
      acc[nt] = __builtin_amdgcn_mfma_f32_16x16x32_f16(aD, bl, acc[nt], 0, 0, 0);
      acc[nt] = __builtin_amdgcn_mfma_f32_16x16x32_f16(aH, br, acc[nt], 0, 0, 0);
    }
  }
  int rbase = row0 + ((lane >> 4) << 2);
  int cl = lane & 15;
#pragma unroll
  for (int nt = 0; nt < 8; ++nt) {
    int col = nt * 16 + cl;
    float bv = bias[col];
#pragma unroll
    for (int r = 0; r < 4; ++r) {
      int row = rbase + r;
      if (row < n) {
        float v = fmaxf(acc[nt][r] + bv, 0.f);
        out[(size_t)row * HID + col] = (half_t)v;
      }
    }
  }
}

// ---------------------------------------------------------------- MFMA single GEMM: ns = h@W + b (f32 out) + block col sums
__global__ __launch_bounds__(256) void k_single_mfma(const half_t* __restrict__ hs,
                                                     const half_t* __restrict__ w,
                                                     const float* __restrict__ bias,
                                                     float* __restrict__ out,
                                                     float* __restrict__ part, int n) {
  __shared__ float colsum[HID];
  int tid = threadIdx.x;
  int lane = tid & 63;
  int wid = tid >> 6;
  if (tid < HID) colsum[tid] = 0.f;
  __syncthreads();
  int row0 = blockIdx.x * 64 + wid * 16;
  bool active = row0 < n;
  f32x4 acc[8];
#pragma unroll
  for (int t = 0; t < 8; ++t) acc[t] = (f32x4){0.f, 0.f, 0.f, 0.f};
  if (active) {
    int arow = row0 + (lane & 15);
    int arowc = arow < n ? arow : n - 1;
    size_t abase = (size_t)arowc * HID + ((lane >> 4) << 3);
    const half8* W8 = (const half8*)w;
#pragma unroll
    for (int ks = 0; ks < 4; ++ks) {
      half8 aH = *(const half8*)&hs[abase + ks * 32];
      int fb = ks * 8;
#pragma unroll
      for (int nt = 0; nt < 8; ++nt) {
        half8 b = W8[(size_t)(fb + nt) * 64 + lane];
        acc[nt] = __builtin_amdgcn_mfma_f32_16x16x32_f16(aH, b, acc[nt], 0, 0, 0);
      }
    }
    int rbase = row0 + ((lane >> 4) << 2);
    int cl = lane & 15;
#pragma unroll
    for (int nt = 0; nt < 8; ++nt) {
      int col = nt * 16 + cl;
      float bv = bias[col];
      float csum = 0.f;
#pragma unroll
      for (int r = 0; r < 4; ++r) {
        int row = rbase + r;
        if (row < n) {
          float v = acc[nt][r] + bv;
          out[(size_t)row * HID + col] = v;
          csum += v;
        }
      }
      atomicAdd(&colsum[col], csum);
    }
  }
  __syncthreads();
  if (tid < HID) part[(size_t)blockIdx.x * HID + tid] = colsum[tid];
}

// ---------------------------------------------------------------- final column reduce
__global__ __launch_bounds__(256) void k_colfinal(const float* __restrict__ part,
                                                  float* __restrict__ outmean,
                                                  int rows, float inv) {
  __shared__ float red[256];
  int t = threadIdx.x;
  int col = t & 127, half = t >> 7;
  int r0 = blockIdx.x * 256;
  float s = 0.f;
  for (int r = half; r < 256; r += 2) {
    int row = r0 + r;
    if (row < rows) s += part[(size_t)row * HID + col];
  }
  red[t] = s;
  __syncthreads();
  if (t < 128) atomicAdd(&outmean[col], (red[t] + red[t + 128]) * inv);
}

// ---------------------------------------------------------------- launch
extern "C" void kernel_launch(void* const* d_in, const int* in_sizes, int n_in,
                              void* d_out, int out_size, void* d_ws, size_t ws_size,
                              hipStream_t stream) {
  const float* pos  = (const float*)d_in[0];
  const int*   an   = (const int*)d_in[1];
  const int*   ei   = (const int*)d_in[2];
  const float* Win  = (const float*)d_in[3];
  const float* bin  = (const float*)d_in[4];
  const float* W1l  = (const float*)d_in[5];
  const float* b1   = (const float*)d_in[6];
  const float* W1r  = (const float*)d_in[7];
  const float* W2l  = (const float*)d_in[8];
  const float* b2   = (const float*)d_in[9];
  const float* W2r  = (const float*)d_in[10];
  const float* Wout = (const float*)d_in[11];
  const float* bout = (const float*)d_in[12];

  int N = in_sizes[0] / 3;
  int E = in_sizes[2] / 2;
  const int* srcl = ei;
  const int* dstl = ei + E;

  float* outmean = (float*)d_out;
  float* ns      = (float*)d_out + HID;

  char* p = (char*)d_ws;
  auto take = [&](size_t bytes) {
    char* q = p;
    p += (bytes + 255) & ~(size_t)255;
    return q;
  };
  int nbuck = (N + BK_NODES - 1) / BK_NODES;       // 196
  half_t*   H0      = (half_t*)take((size_t)(N + 1) * HID * 2);   // +1 zero row
  half_t*   H1      = (half_t*)take((size_t)(N + 1) * HID * 2);   // +1 zero row
  half_t*   H2      = (half_t*)take((size_t)N * HID * 2);
  half_t*   D       = (half_t*)take((size_t)N * HID * 2);
  int*      offs    = (int*)take((size_t)N * 4);
  int*      offsE   = (int*)take((size_t)N * 4);
  int*      csr     = (int*)take((size_t)nbuck * BKCAP * 4);
  unsigned* ebuf    = (unsigned*)take((size_t)nbuck * BKCAP * 4);
  int*      bcur    = (int*)take((size_t)256 * 4);
  half_t*   pW1l    = (half_t*)take((size_t)16384 * 2);
  half_t*   pW1r    = (half_t*)take((size_t)16384 * 2);
  half_t*   pW2l    = (half_t*)take((size_t)16384 * 2);
  half_t*   pW2r    = (half_t*)take((size_t)16384 * 2);
  half_t*   pWout   = (half_t*)take((size_t)16384 * 2);
  int gSage = (N + 63) / 64;
  float*    colpart = (float*)take((size_t)gSage * HID * 4);

  int gEmbed = (int)(((size_t)N * 32 + 255) / 256);
  int gWave  = (N + 3) / 4;
  int gBktA  = (E + EDGES_PER_BLKA - 1) / EDGES_PER_BLKA;

  k_init<<<1, 256, 0, stream>>>(bcur, outmean, &H0[(size_t)N * HID], &H1[(size_t)N * HID]);
  k_packW5<<<40, 256, 0, stream>>>(W1l, W1r, W2l, W2r, Wout,
                                   pW1l, pW1r, pW2l, pW2r, pWout);
  k_embed<<<gEmbed, 256, 0, stream>>>(pos, an, Win, bin, H0, N);
  k_bucketA<<<gBktA, 1024, 0, stream>>>(srcl, dstl, bcur, ebuf, E);
  k_bucketB<<<nbuck, 256, 0, stream>>>(ebuf, bcur, offs, offsE, csr, N);

  // conv1
  k_aggmean_f16<<<gWave, 256, 0, stream>>>(H0, csr, offs, offsE, D, N);
  k_sage_mfma<<<gSage, 256, 0, stream>>>(D, H0, pW1l, pW1r, b1, H1, N);
  // conv2
  k_aggmean_f16<<<gWave, 256, 0, stream>>>(H1, csr, offs, offsE, D, N);
  k_sage_mfma<<<gSage, 256, 0, stream>>>(D, H1, pW2l, pW2r, b2, H2, N);
  // output projection + column mean
  k_single_mfma<<<gSage, 256, 0, stream>>>(H2, pWout, bout, ns, colpart, N);
  k_colfinal<<<(gSage + 255) / 256, 256, 0, stream>>>(colpart, outmean, gSage, 1.0f / (float)N);
}

// Round 14
// 294.513 us; speedup vs baseline: 1.0937x; 1.0483x over previous
//
#include <hip/hip_runtime.h>

#define HID 128
#define BK_SHIFT 9            // 512 nodes per bucket
#define BK_NODES 512
#define BKCAP 10240           // padded slots per bucket (mean 8192, sigma ~90)
#define EDGES_PER_BLKA 8192

typedef _Float16 half_t;
typedef __attribute__((ext_vector_type(8))) _Float16 half8;
typedef __attribute__((ext_vector_type(4))) _Float16 half4;
typedef __attribute__((ext_vector_type(4))) float f32x4;

// ---------------------------------------------------------------- fused setup: embed | packW x5 | init
// blocks [0, gEmbed): embed; [gEmbed, gEmbed+40): pack 5 weights; gEmbed+40: init cursors/outmean/zero-rows
__global__ __launch_bounds__(256) void k_setup(const float* __restrict__ pos,
                                               const int* __restrict__ an,
                                               const float* __restrict__ Win,
                                               const float* __restrict__ bin,
                                               half_t* __restrict__ h0,
                                               const float* __restrict__ w0,
                                               const float* __restrict__ w1,
                                               const float* __restrict__ w2,
                                               const float* __restrict__ w3,
                                               const float* __restrict__ w4,
                                               half_t* __restrict__ o0,
                                               half_t* __restrict__ o1,
                                               half_t* __restrict__ o2,
                                               half_t* __restrict__ o3,
                                               half_t* __restrict__ o4,
                                               int* __restrict__ bcur,
                                               float* __restrict__ outmean,
                                               half_t* __restrict__ h0z,
                                               half_t* __restrict__ h1z,
                                               int n, int gEmbed) {
  int bid = blockIdx.x;
  if (bid < gEmbed) {
    // ---- embed: h0 = relu([z,pos] @ W_in + b_in) -> fp16
    int t = bid * 256 + threadIdx.x;
    int i = t >> 5, cg = t & 31;
    if (i >= n) return;
    int j0 = cg << 2;
    float z  = (float)an[i] / 10.0f;
    float px = pos[3 * i + 0], py = pos[3 * i + 1], pz = pos[3 * i + 2];
    float4 ww0 = *(const float4*)&Win[0 * HID + j0];
    float4 ww1 = *(const float4*)&Win[1 * HID + j0];
    float4 ww2 = *(const float4*)&Win[2 * HID + j0];
    float4 ww3 = *(const float4*)&Win[3 * HID + j0];
    float4 b   = *(const float4*)&bin[j0];
    float4 o;
    o.x = fmaxf(fmaf(z, ww0.x, fmaf(px, ww1.x, fmaf(py, ww2.x, fmaf(pz, ww3.x, b.x)))), 0.f);
    o.y = fmaxf(fmaf(z, ww0.y, fmaf(px, ww1.y, fmaf(py, ww2.y, fmaf(pz, ww3.y, b.y)))), 0.f);
    o.z = fmaxf(fmaf(z, ww0.z, fmaf(px, ww1.z, fmaf(py, ww2.z, fmaf(pz, ww3.z, b.z)))), 0.f);
    o.w = fmaxf(fmaf(z, ww0.w, fmaf(px, ww1.w, fmaf(py, ww2.w, fmaf(pz, ww3.w, b.w)))), 0.f);
    half4 ph;
    ph.x = (half_t)o.x; ph.y = (half_t)o.y; ph.z = (half_t)o.z; ph.w = (half_t)o.w;
    *(half4*)&h0[(size_t)i * HID + j0] = ph;
  } else if (bid < gEmbed + 40) {
    // ---- pack W [128][128] f32 -> MFMA B-fragment fp16
    int pb = bid - gEmbed;
    int m = pb >> 3;
    const float* W = (m == 0) ? w0 : (m == 1) ? w1 : (m == 2) ? w2 : (m == 3) ? w3 : w4;
    half_t* out = (m == 0) ? o0 : (m == 1) ? o1 : (m == 2) ? o2 : (m == 3) ? o3 : o4;
    int tid = (pb & 7) * 256 + threadIdx.x;   // 0..2047
    int lane = tid & 63;
    int frag = tid >> 6;                      // 0..31
    int ks = frag >> 3, nt = frag & 7;
    int k0 = ks * 32 + ((lane >> 4) << 3);
    int col = nt * 16 + (lane & 15);
    half8 v;
#pragma unroll
    for (int i = 0; i < 8; ++i) v[i] = (half_t)W[(k0 + i) * HID + col];
    *(half8*)&out[(size_t)tid * 8] = v;
  } else {
    // ---- init
    int i = threadIdx.x;
    bcur[i] = i * BKCAP;
    if (i < HID) outmean[i] = 0.f;
    if (i < HID) h0z[i] = (half_t)0.f;
    else         h1z[i - HID] = (half_t)0.f;
  }
}

// ---------------------------------------------------------------- pass A: bin edges into padded dst-buckets
__global__ __launch_bounds__(1024) void k_bucketA(const int* __restrict__ src,
                                                  const int* __restrict__ dst,
                                                  int* __restrict__ bcur,
                                                  unsigned* __restrict__ ebuf,
                                                  int e) {
  __shared__ int hist[256];
  __shared__ int resv[256];
  int t = threadIdx.x;
  if (t < 256) hist[t] = 0;
  __syncthreads();
  int e0 = blockIdx.x * EDGES_PER_BLKA;
  int myb[8], myr[8];
  unsigned mypk[8];
#pragma unroll
  for (int i = 0; i < 8; ++i) {
    int idx = e0 + i * 1024 + t;
    if (idx < e) {
      int d = dst[idx];
      int s = src[idx];
      int b = d >> BK_SHIFT;
      myb[i] = b;
      myr[i] = atomicAdd(&hist[b], 1);
      mypk[i] = ((unsigned)s << BK_SHIFT) | (unsigned)(d & (BK_NODES - 1));
    } else {
      myb[i] = -1;
    }
  }
  __syncthreads();
  if (t < 256) resv[t] = (hist[t] > 0) ? atomicAdd(&bcur[t], hist[t]) : 0;
  __syncthreads();
#pragma unroll
  for (int i = 0; i < 8; ++i) {
    if (myb[i] >= 0) ebuf[resv[myb[i]] + myr[i]] = mypk[i];
  }
}

// ---------------------------------------------------------------- pass B: per bucket (512 threads): LDS hist -> scan -> offs + csr
__global__ __launch_bounds__(512) void k_bucketB(const unsigned* __restrict__ ebuf,
                                                 const int* __restrict__ bkend,
                                                 int* __restrict__ offs,
                                                 int* __restrict__ offsE,
                                                 int* __restrict__ csr, int n) {
  __shared__ int hist[BK_NODES];
  __shared__ int red[BK_NODES];
  int b = blockIdx.x;
  int n0 = b << BK_SHIFT;
  int t = threadIdx.x;
  int ebeg = b * BKCAP, eend = bkend[b];
  hist[t] = 0;
  __syncthreads();
  // pass 1: count local dst
  for (int idx = ebeg + t; idx < eend; idx += 512) {
    atomicAdd(&hist[ebuf[idx] & (BK_NODES - 1)], 1);
  }
  __syncthreads();
  int h0 = hist[t];
  red[t] = h0;
  __syncthreads();
  for (int d = 1; d < 512; d <<= 1) {
    int u = (t >= d) ? red[t - d] : 0;
    __syncthreads();
    red[t] += u;
    __syncthreads();
  }
  int base0 = ebeg + (red[t] - h0);   // exclusive
  int g = n0 + t;
  if (g < n) { offs[g] = base0; offsE[g] = base0 + h0; }
  __syncthreads();
  hist[t] = base0;
  __syncthreads();
  // pass 2: scatter into csr (~64KB window per block)
  for (int idx = ebeg + t; idx < eend; idx += 512) {
    unsigned pk = ebuf[idx];
    int dl = pk & (BK_NODES - 1);
    int slot = atomicAdd(&hist[dl], 1);
    csr[slot] = (int)(pk >> BK_SHIFT);
  }
}

// ---------------------------------------------------------------- mean aggregation, 16 lanes/edge-row, dwordx4 loads,
// 4x unrolled: 4 independent row-gathers in flight per lane (16 edges/wave)
__global__ __launch_bounds__(256) void k_aggmean_f16(const half_t* __restrict__ h,
                                                     const int* __restrict__ csr,
                                                     const int* __restrict__ offs,
                                                     const int* __restrict__ offsE,
                                                     half_t* __restrict__ out, int n) {
  int w = (blockIdx.x * 256 + threadIdx.x) >> 6;
  int lane = threadIdx.x & 63;
  if (w >= n) return;
  int cs = lane & 15, es = lane >> 4;
  int beg = offs[w], end = offsE[w];
  size_t coff = (size_t)(cs * 8);
  float acc[8];
#pragma unroll
  for (int j = 0; j < 8; ++j) acc[j] = 0.f;
  int e = beg;
  for (; e + 16 <= end; e += 16) {
    int s0 = csr[e + es];
    int s1 = csr[e + 4 + es];
    int s2 = csr[e + 8 + es];
    int s3 = csr[e + 12 + es];
    half8 v0 = *(const half8*)&h[(size_t)s0 * HID + coff];
    half8 v1 = *(const half8*)&h[(size_t)s1 * HID + coff];
    half8 v2 = *(const half8*)&h[(size_t)s2 * HID + coff];
    half8 v3 = *(const half8*)&h[(size_t)s3 * HID + coff];
#pragma unroll
    for (int j = 0; j < 8; ++j)
      acc[j] += ((float)v0[j] + (float)v1[j]) + ((float)v2[j] + (float)v3[j]);
  }
  for (; e < end; e += 4) {
    int ee = e + es;
    if (ee < end) {
      int s = csr[ee];
      half8 v = *(const half8*)&h[(size_t)s * HID + coff];
#pragma unroll
      for (int j = 0; j < 8; ++j) acc[j] += (float)v[j];
    }
  }
#pragma unroll
  for (int j = 0; j < 8; ++j) {
    acc[j] += __shfl_xor(acc[j], 16, 64);
    acc[j] += __shfl_xor(acc[j], 32, 64);
  }
  if (es == 0) {
    int c = end - beg;
    float inv = (c > 0) ? 1.0f / (float)c : 0.0f;
    half8 o;
#pragma unroll
    for (int j = 0; j < 8; ++j) o[j] = (half_t)(acc[j] * inv);
    *(half8*)&out[(size_t)w * HID + coff] = o;
  }
}

// ---------------------------------------------------------------- MFMA SAGE: out = relu(ha@Wl + hs@Wr + b), fp16 in/out
__global__ __launch_bounds__(256) void k_sage_mfma(const half_t* __restrict__ ha,
                                                   const half_t* __restrict__ hs,
                                                   const half_t* __restrict__ wl,
                                                   const half_t* __restrict__ wr,
                                                   const float* __restrict__ bias,
                                                   half_t* __restrict__ out, int n) {
  int lane = threadIdx.x & 63;
  int wid = threadIdx.x >> 6;
  int row0 = blockIdx.x * 64 + wid * 16;
  if (row0 >= n) return;
  int arow = row0 + (lane & 15);
  int arowc = arow < n ? arow : n - 1;   // clamp; rows >= n never stored
  size_t abase = (size_t)arowc * HID + ((lane >> 4) << 3);
  const half8* WL = (const half8*)wl;
  const half8* WR = (const half8*)wr;
  f32x4 acc[8];
#pragma unroll
  for (int t = 0; t < 8; ++t) acc[t] = (f32x4){0.f, 0.f, 0.f, 0.f};
#pragma unroll
  for (int ks = 0; ks < 4; ++ks) {
    half8 aD = *(const half8*)&ha[abase + ks * 32];
    half8 aH = *(const half8*)&hs[abase + ks * 32];
    int fb = ks * 8;
#pragma unroll
    for (int nt = 0; nt < 8; ++nt) {
      half8 bl = WL[(size_t)(fb + nt) * 64 + lane];
      half8 br = WR[(size_t)(fb + nt) * 64 + lane];
      acc[nt] = __builtin_amdgcn_mfma_f32_16x16x32_f16(aD, bl, acc[nt], 0, 0, 0);
      acc[nt] = __builtin_amdgcn_mfma_f32_16x16x32_f16(aH, br, acc[nt], 0, 0, 0);
    }
  }
  int rbase = row0 + ((lane >> 4) << 2);
  int cl = lane & 15;
#pragma unroll
  for (int nt = 0; nt < 8; ++nt) {
    int col = nt * 16 + cl;
    float bv = bias[col];
#pragma unroll
    for (int r = 0; r < 4; ++r) {
      int row = rbase + r;
      if (row < n) {
        float v = fmaxf(acc[nt][r] + bv, 0.f);
        out[(size_t)row * HID + col] = (half_t)v;
      }
    }
  }
}

// ---------------------------------------------------------------- MFMA single GEMM: ns = h@W + b (f32 out) + block col sums
__global__ __launch_bounds__(256) void k_single_mfma(const half_t* __restrict__ hs,
                                                     const half_t* __restrict__ w,
                                                     const float* __restrict__ bias,
                                                     float* __restrict__ out,
                                                     float* __restrict__ part, int n) {
  __shared__ float colsum[HID];
  int tid = threadIdx.x;
  int lane = tid & 63;
  int wid = tid >> 6;
  if (tid < HID) colsum[tid] = 0.f;
  __syncthreads();
  int row0 = blockIdx.x * 64 + wid * 16;
  bool active = row0 < n;
  f32x4 acc[8];
#pragma unroll
  for (int t = 0; t < 8; ++t) acc[t] = (f32x4){0.f, 0.f, 0.f, 0.f};
  if (active) {
    int arow = row0 + (lane & 15);
    int arowc = arow < n ? arow : n - 1;
    size_t abase = (size_t)arowc * HID + ((lane >> 4) << 3);
    const half8* W8 = (const half8*)w;
#pragma unroll
    for (int ks = 0; ks < 4; ++ks) {
      half8 aH = *(const half8*)&hs[abase + ks * 32];
      int fb = ks * 8;
#pragma unroll
      for (int nt = 0; nt < 8; ++nt) {
        half8 b = W8[(size_t)(fb + nt) * 64 + lane];
        acc[nt] = __builtin_amdgcn_mfma_f32_16x16x32_f16(aH, b, acc[nt], 0, 0, 0);
      }
    }
    int rbase = row0 + ((lane >> 4) << 2);
    int cl = lane & 15;
#pragma unroll
    for (int nt = 0; nt < 8; ++nt) {
      int col = nt * 16 + cl;
      float bv = bias[col];
      float csum = 0.f;
#pragma unroll
      for (int r = 0; r < 4; ++r) {
        int row = rbase + r;
        if (row < n) {
          float v = acc[nt][r] + bv;
          out[(size_t)row * HID + col] = v;
          csum += v;
        }
      }
      atomicAdd(&colsum[col], csum);
    }
  }
  __syncthreads();
  if (tid < HID) part[(size_t)blockIdx.x * HID + tid] = colsum[tid];
}

// ---------------------------------------------------------------- final column reduce
__global__ __launch_bounds__(256) void k_colfinal(const float* __restrict__ part,
                                                  float* __restrict__ outmean,
                                                  int rows, float inv) {
  __shared__ float red[256];
  int t = threadIdx.x;
  int col = t & 127, half = t >> 7;
  int r0 = blockIdx.x * 256;
  float s = 0.f;
  for (int r = half; r < 256; r += 2) {
    int row = r0 + r;
    if (row < rows) s += part[(size_t)row * HID + col];
  }
  red[t] = s;
  __syncthreads();
  if (t < 128) atomicAdd(&outmean[col], (red[t] + red[t + 128]) * inv);
}

// ---------------------------------------------------------------- launch
extern "C" void kernel_launch(void* const* d_in, const int* in_sizes, int n_in,
                              void* d_out, int out_size, void* d_ws, size_t ws_size,
                              hipStream_t stream) {
  const float* pos  = (const float*)d_in[0];
  const int*   an   = (const int*)d_in[1];
  const int*   ei   = (const int*)d_in[2];
  const float* Win  = (const float*)d_in[3];
  const float* bin  = (const float*)d_in[4];
  const float* W1l  = (const float*)d_in[5];
  const float* b1   = (const float*)d_in[6];
  const float* W1r  = (const float*)d_in[7];
  const float* W2l  = (const float*)d_in[8];
  const float* b2   = (const float*)d_in[9];
  const float* W2r  = (const float*)d_in[10];
  const float* Wout = (const float*)d_in[11];
  const float* bout = (const float*)d_in[12];

  int N = in_sizes[0] / 3;
  int E = in_sizes[2] / 2;
  const int* srcl = ei;
  const int* dstl = ei + E;

  float* outmean = (float*)d_out;
  float* ns      = (float*)d_out + HID;

  char* p = (char*)d_ws;
  auto take = [&](size_t bytes) {
    char* q = p;
    p += (bytes + 255) & ~(size_t)255;
    return q;
  };
  int nbuck = (N + BK_NODES - 1) / BK_NODES;       // 196
  half_t*   H0      = (half_t*)take((size_t)(N + 1) * HID * 2);   // +1 zero row
  half_t*   H1      = (half_t*)take((size_t)(N + 1) * HID * 2);   // +1 zero row
  half_t*   H2      = (half_t*)take((size_t)N * HID * 2);
  half_t*   D       = (half_t*)take((size_t)N * HID * 2);
  int*      offs    = (int*)take((size_t)N * 4);
  int*      offsE   = (int*)take((size_t)N * 4);
  int*      csr     = (int*)take((size_t)nbuck * BKCAP * 4);
  unsigned* ebuf    = (unsigned*)take((size_t)nbuck * BKCAP * 4);
  int*      bcur    = (int*)take((size_t)256 * 4);
  half_t*   pW1l    = (half_t*)take((size_t)16384 * 2);
  half_t*   pW1r    = (half_t*)take((size_t)16384 * 2);
  half_t*   pW2l    = (half_t*)take((size_t)16384 * 2);
  half_t*   pW2r    = (half_t*)take((size_t)16384 * 2);
  half_t*   pWout   = (half_t*)take((size_t)16384 * 2);
  int gSage = (N + 63) / 64;
  float*    colpart = (float*)take((size_t)gSage * HID * 4);

  int gEmbed = (int)(((size_t)N * 32 + 255) / 256);
  int gWave  = (N + 3) / 4;
  int gBktA  = (E + EDGES_PER_BLKA - 1) / EDGES_PER_BLKA;

  k_setup<<<gEmbed + 41, 256, 0, stream>>>(pos, an, Win, bin, H0,
                                           W1l, W1r, W2l, W2r, Wout,
                                           pW1l, pW1r, pW2l, pW2r, pWout,
                                           bcur, outmean,
                                           &H0[(size_t)N * HID], &H1[(size_t)N * HID],
                                           N, gEmbed);
  k_bucketA<<<gBktA, 1024, 0, stream>>>(srcl, dstl, bcur, ebuf, E);
  k_bucketB<<<nbuck, 512, 0, stream>>>(ebuf, bcur, offs, offsE, csr, N);

  // conv1
  k_aggmean_f16<<<gWave, 256, 0, stream>>>(H0, csr, offs, offsE, D, N);
  k_sage_mfma<<<gSage, 256, 0, stream>>>(D, H0, pW1l, pW1r, b1, H1, N);
  // conv2
  k_aggmean_f16<<<gWave, 256, 0, stream>>>(H1, csr, offs, offsE, D, N);
  k_sage_mfma<<<gSage, 256, 0, stream>>>(D, H1, pW2l, pW2r, b2, H2, N);
  // output projection + column mean
  k_single_mfma<<<gSage, 256, 0, stream>>>(H2, pWout, bout, ns, colpart, N);
  k_colfinal<<<(gSage + 255) / 256, 256, 0, stream>>>(colpart, outmean, gSage, 1.0f / (float)N);
}

// Round 15
// 278.381 us; speedup vs baseline: 1.1571x; 1.0579x over previous
//
#include <hip/hip_runtime.h>

#define HID 128
#define BK_SHIFT 9            // 512 nodes per bucket
#define BK_NODES 512
#define BKCAP 10240           // padded slots per bucket (mean 8192, sigma ~90)
#define EDGES_PER_BLKA 8192

typedef _Float16 half_t;
typedef __attribute__((ext_vector_type(8))) _Float16 half8;
typedef __attribute__((ext_vector_type(4))) _Float16 half4;
typedef __attribute__((ext_vector_type(4))) float f32x4;

// ---------------------------------------------------------------- fused setup: embed | packW x5 | init
__global__ __launch_bounds__(256) void k_setup(const float* __restrict__ pos,
                                               const int* __restrict__ an,
                                               const float* __restrict__ Win,
                                               const float* __restrict__ bin,
                                               half_t* __restrict__ h0,
                                               const float* __restrict__ w0,
                                               const float* __restrict__ w1,
                                               const float* __restrict__ w2,
                                               const float* __restrict__ w3,
                                               const float* __restrict__ w4,
                                               half_t* __restrict__ o0,
                                               half_t* __restrict__ o1,
                                               half_t* __restrict__ o2,
                                               half_t* __restrict__ o3,
                                               half_t* __restrict__ o4,
                                               int* __restrict__ bcur,
                                               float* __restrict__ outmean,
                                               half_t* __restrict__ h0z,
                                               half_t* __restrict__ h1z,
                                               int n, int gEmbed) {
  int bid = blockIdx.x;
  if (bid < gEmbed) {
    int t = bid * 256 + threadIdx.x;
    int i = t >> 5, cg = t & 31;
    if (i >= n) return;
    int j0 = cg << 2;
    float z  = (float)an[i] / 10.0f;
    float px = pos[3 * i + 0], py = pos[3 * i + 1], pz = pos[3 * i + 2];
    float4 ww0 = *(const float4*)&Win[0 * HID + j0];
    float4 ww1 = *(const float4*)&Win[1 * HID + j0];
    float4 ww2 = *(const float4*)&Win[2 * HID + j0];
    float4 ww3 = *(const float4*)&Win[3 * HID + j0];
    float4 b   = *(const float4*)&bin[j0];
    float4 o;
    o.x = fmaxf(fmaf(z, ww0.x, fmaf(px, ww1.x, fmaf(py, ww2.x, fmaf(pz, ww3.x, b.x)))), 0.f);
    o.y = fmaxf(fmaf(z, ww0.y, fmaf(px, ww1.y, fmaf(py, ww2.y, fmaf(pz, ww3.y, b.y)))), 0.f);
    o.z = fmaxf(fmaf(z, ww0.z, fmaf(px, ww1.z, fmaf(py, ww2.z, fmaf(pz, ww3.z, b.z)))), 0.f);
    o.w = fmaxf(fmaf(z, ww0.w, fmaf(px, ww1.w, fmaf(py, ww2.w, fmaf(pz, ww3.w, b.w)))), 0.f);
    half4 ph;
    ph.x = (half_t)o.x; ph.y = (half_t)o.y; ph.z = (half_t)o.z; ph.w = (half_t)o.w;
    *(half4*)&h0[(size_t)i * HID + j0] = ph;
  } else if (bid < gEmbed + 40) {
    int pb = bid - gEmbed;
    int m = pb >> 3;
    const float* W = (m == 0) ? w0 : (m == 1) ? w1 : (m == 2) ? w2 : (m == 3) ? w3 : w4;
    half_t* out = (m == 0) ? o0 : (m == 1) ? o1 : (m == 2) ? o2 : (m == 3) ? o3 : o4;
    int tid = (pb & 7) * 256 + threadIdx.x;   // 0..2047
    int lane = tid & 63;
    int frag = tid >> 6;                      // 0..31
    int ks = frag >> 3, nt = frag & 7;
    int k0 = ks * 32 + ((lane >> 4) << 3);
    int col = nt * 16 + (lane & 15);
    half8 v;
#pragma unroll
    for (int i = 0; i < 8; ++i) v[i] = (half_t)W[(k0 + i) * HID + col];
    *(half8*)&out[(size_t)tid * 8] = v;
  } else {
    int i = threadIdx.x;
    bcur[i] = i * BKCAP;
    if (i < HID) outmean[i] = 0.f;
    if (i < HID) h0z[i] = (half_t)0.f;
    else         h1z[i - HID] = (half_t)0.f;
  }
}

// ---------------------------------------------------------------- pass A: bin edges into padded dst-buckets
// each thread handles 8 CONTIGUOUS edges via int4 loads (32B/lane)
__global__ __launch_bounds__(1024) void k_bucketA(const int* __restrict__ src,
                                                  const int* __restrict__ dst,
                                                  int* __restrict__ bcur,
                                                  unsigned* __restrict__ ebuf,
                                                  int e) {
  __shared__ int hist[256];
  __shared__ int resv[256];
  int t = threadIdx.x;
  if (t < 256) hist[t] = 0;
  __syncthreads();
  int base = blockIdx.x * EDGES_PER_BLKA + t * 8;
  int myb[8], myr[8];
  unsigned mypk[8];
  if (base + 8 <= e) {
    int4 sa = *(const int4*)&src[base];
    int4 sb = *(const int4*)&src[base + 4];
    int4 da = *(const int4*)&dst[base];
    int4 db = *(const int4*)&dst[base + 4];
    int ss[8] = {sa.x, sa.y, sa.z, sa.w, sb.x, sb.y, sb.z, sb.w};
    int dd[8] = {da.x, da.y, da.z, da.w, db.x, db.y, db.z, db.w};
#pragma unroll
    for (int i = 0; i < 8; ++i) {
      int b = dd[i] >> BK_SHIFT;
      myb[i] = b;
      myr[i] = atomicAdd(&hist[b], 1);
      mypk[i] = ((unsigned)ss[i] << BK_SHIFT) | (unsigned)(dd[i] & (BK_NODES - 1));
    }
  } else {
#pragma unroll
    for (int i = 0; i < 8; ++i) {
      int idx = base + i;
      if (idx < e) {
        int d = dst[idx];
        int s = src[idx];
        int b = d >> BK_SHIFT;
        myb[i] = b;
        myr[i] = atomicAdd(&hist[b], 1);
        mypk[i] = ((unsigned)s << BK_SHIFT) | (unsigned)(d & (BK_NODES - 1));
      } else {
        myb[i] = -1;
      }
    }
  }
  __syncthreads();
  if (t < 256) resv[t] = (hist[t] > 0) ? atomicAdd(&bcur[t], hist[t]) : 0;
  __syncthreads();
#pragma unroll
  for (int i = 0; i < 8; ++i) {
    if (myb[i] >= 0) ebuf[resv[myb[i]] + myr[i]] = mypk[i];
  }
}

// ---------------------------------------------------------------- pass B: per bucket (512 threads): LDS hist -> scan -> offs + csr
// uint4-vectorized ebuf sweeps
__global__ __launch_bounds__(512) void k_bucketB(const unsigned* __restrict__ ebuf,
                                                 const int* __restrict__ bkend,
                                                 int* __restrict__ offs,
                                                 int* __restrict__ offsE,
                                                 int* __restrict__ csr, int n) {
  __shared__ int hist[BK_NODES];
  __shared__ int red[BK_NODES];
  int b = blockIdx.x;
  int n0 = b << BK_SHIFT;
  int t = threadIdx.x;
  int ebeg = b * BKCAP, eend = bkend[b];
  hist[t] = 0;
  __syncthreads();
  // pass 1: count local dst (uint4)
  for (int idx = ebeg + t * 4; idx < eend; idx += 2048) {
    if (idx + 4 <= eend) {
      uint4 pk = *(const uint4*)&ebuf[idx];
      atomicAdd(&hist[pk.x & (BK_NODES - 1)], 1);
      atomicAdd(&hist[pk.y & (BK_NODES - 1)], 1);
      atomicAdd(&hist[pk.z & (BK_NODES - 1)], 1);
      atomicAdd(&hist[pk.w & (BK_NODES - 1)], 1);
    } else {
      for (int k = 0; k < 4; ++k) {
        int id2 = idx + k;
        if (id2 < eend) atomicAdd(&hist[ebuf[id2] & (BK_NODES - 1)], 1);
      }
    }
  }
  __syncthreads();
  int h0 = hist[t];
  red[t] = h0;
  __syncthreads();
  for (int d = 1; d < 512; d <<= 1) {
    int u = (t >= d) ? red[t - d] : 0;
    __syncthreads();
    red[t] += u;
    __syncthreads();
  }
  int base0 = ebeg + (red[t] - h0);   // exclusive
  int g = n0 + t;
  if (g < n) { offs[g] = base0; offsE[g] = base0 + h0; }
  __syncthreads();
  hist[t] = base0;
  __syncthreads();
  // pass 2: scatter into csr (uint4 reads, ~64KB write window)
  for (int idx = ebeg + t * 4; idx < eend; idx += 2048) {
    if (idx + 4 <= eend) {
      uint4 pk = *(const uint4*)&ebuf[idx];
      csr[atomicAdd(&hist[pk.x & (BK_NODES - 1)], 1)] = (int)(pk.x >> BK_SHIFT);
      csr[atomicAdd(&hist[pk.y & (BK_NODES - 1)], 1)] = (int)(pk.y >> BK_SHIFT);
      csr[atomicAdd(&hist[pk.z & (BK_NODES - 1)], 1)] = (int)(pk.z >> BK_SHIFT);
      csr[atomicAdd(&hist[pk.w & (BK_NODES - 1)], 1)] = (int)(pk.w >> BK_SHIFT);
    } else {
      for (int k = 0; k < 4; ++k) {
        int id2 = idx + k;
        if (id2 < eend) {
          unsigned pk = ebuf[id2];
          csr[atomicAdd(&hist[pk & (BK_NODES - 1)], 1)] = (int)(pk >> BK_SHIFT);
        }
      }
    }
  }
}

// ---------------------------------------------------------------- mean aggregation, 16 lanes/edge-row, dwordx4 loads
__global__ __launch_bounds__(256) void k_aggmean_f16(const half_t* __restrict__ h,
                                                     const int* __restrict__ csr,
                                                     const int* __restrict__ offs,
                                                     const int* __restrict__ offsE,
                                                     half_t* __restrict__ out, int n) {
  int w = (blockIdx.x * 256 + threadIdx.x) >> 6;
  int lane = threadIdx.x & 63;
  if (w >= n) return;
  int cs = lane & 15, es = lane >> 4;
  int beg = offs[w], end = offsE[w];
  size_t coff = (size_t)(cs * 8);
  float acc[8];
#pragma unroll
  for (int j = 0; j < 8; ++j) acc[j] = 0.f;
  int e = beg;
  for (; e + 16 <= end; e += 16) {
    int s0 = csr[e + es];
    int s1 = csr[e + 4 + es];
    int s2 = csr[e + 8 + es];
    int s3 = csr[e + 12 + es];
    half8 v0 = *(const half8*)&h[(size_t)s0 * HID + coff];
    half8 v1 = *(const half8*)&h[(size_t)s1 * HID + coff];
    half8 v2 = *(const half8*)&h[(size_t)s2 * HID + coff];
    half8 v3 = *(const half8*)&h[(size_t)s3 * HID + coff];
#pragma unroll
    for (int j = 0; j < 8; ++j)
      acc[j] += ((float)v0[j] + (float)v1[j]) + ((float)v2[j] + (float)v3[j]);
  }
  for (; e < end; e += 4) {
    int ee = e + es;
    if (ee < end) {
      int s = csr[ee];
      half8 v = *(const half8*)&h[(size_t)s * HID + coff];
#pragma unroll
      for (int j = 0; j < 8; ++j) acc[j] += (float)v[j];
    }
  }
#pragma unroll
  for (int j = 0; j < 8; ++j) {
    acc[j] += __shfl_xor(acc[j], 16, 64);
    acc[j] += __shfl_xor(acc[j], 32, 64);
  }
  if (es == 0) {
    int c = end - beg;
    float inv = (c > 0) ? 1.0f / (float)c : 0.0f;
    half8 o;
#pragma unroll
    for (int j = 0; j < 8; ++j) o[j] = (half_t)(acc[j] * inv);
    *(half8*)&out[(size_t)w * HID + coff] = o;
  }
}

// ---------------------------------------------------------------- MFMA SAGE (conv1): out = relu(ha@Wl + hs@Wr + b), fp16
__global__ __launch_bounds__(256) void k_sage_mfma(const half_t* __restrict__ ha,
                                                   const half_t* __restrict__ hs,
                                                   const half_t* __restrict__ wl,
                                                   const half_t* __restrict__ wr,
                                                   const float* __restrict__ bias,
                                                   half_t* __restrict__ out, int n) {
  int lane = threadIdx.x & 63;
  int wid = threadIdx.x >> 6;
  int row0 = blockIdx.x * 64 + wid * 16;
  if (row0 >= n) return;
  int arow = row0 + (lane & 15);
  int arowc = arow < n ? arow : n - 1;
  size_t abase = (size_t)arowc * HID + ((lane >> 4) << 3);
  const half8* WL = (const half8*)wl;
  const half8* WR = (const half8*)wr;
  f32x4 acc[8];
#pragma unroll
  for (int t = 0; t < 8; ++t) acc[t] = (f32x4){0.f, 0.f, 0.f, 0.f};
#pragma unroll
  for (int ks = 0; ks < 4; ++ks) {
    half8 aD = *(const half8*)&ha[abase + ks * 32];
    half8 aH = *(const half8*)&hs[abase + ks * 32];
    int fb = ks * 8;
#pragma unroll
    for (int nt = 0; nt < 8; ++nt) {
      half8 bl = WL[(size_t)(fb + nt) * 64 + lane];
      half8 br = WR[(size_t)(fb + nt) * 64 + lane];
      acc[nt] = __builtin_amdgcn_mfma_f32_16x16x32_f16(aD, bl, acc[nt], 0, 0, 0);
      acc[nt] = __builtin_amdgcn_mfma_f32_16x16x32_f16(aH, br, acc[nt], 0, 0, 0);
    }
  }
  int rbase = row0 + ((lane >> 4) << 2);
  int cl = lane & 15;
#pragma unroll
  for (int nt = 0; nt < 8; ++nt) {
    int col = nt * 16 + cl;
    float bv = bias[col];
#pragma unroll
    for (int r = 0; r < 4; ++r) {
      int row = rbase + r;
      if (row < n) {
        float v = fmaxf(acc[nt][r] + bv, 0.f);
        out[(size_t)row * HID + col] = (half_t)v;
      }
    }
  }
}

// ---------------------------------------------------------------- fused conv2 GEMM + output projection + col partials
// h2 = relu(ha@W2l + hs@W2r + b2) stays in registers -> LDS -> ns = h2@Wout + bout; partial col sums
__global__ __launch_bounds__(256) void k_sage_out(const half_t* __restrict__ ha,
                                                  const half_t* __restrict__ hs,
                                                  const half_t* __restrict__ wl,
                                                  const half_t* __restrict__ wr,
                                                  const float* __restrict__ bias2,
                                                  const half_t* __restrict__ wout,
                                                  const float* __restrict__ bout,
                                                  float* __restrict__ out,
                                                  float* __restrict__ part, int n) {
  __shared__ half_t Hs[64][132];    // 264B row stride -> <=4-way bank aliasing on b128 reads
  __shared__ float colsum[HID];
  int tid = threadIdx.x;
  int lane = tid & 63;
  int wid = tid >> 6;
  if (tid < HID) colsum[tid] = 0.f;
  int row0 = blockIdx.x * 64 + wid * 16;
  bool active = row0 < n;

  // ---- phase 1: conv2 GEMM, result -> LDS stripe (per-wave exclusive)
  if (active) {
    int arow = row0 + (lane & 15);
    int arowc = arow < n ? arow : n - 1;
    size_t abase = (size_t)arowc * HID + ((lane >> 4) << 3);
    const half8* WL = (const half8*)wl;
    const half8* WR = (const half8*)wr;
    f32x4 acc[8];
#pragma unroll
    for (int t = 0; t < 8; ++t) acc[t] = (f32x4){0.f, 0.f, 0.f, 0.f};
#pragma unroll
    for (int ks = 0; ks < 4; ++ks) {
      half8 aD = *(const half8*)&ha[abase + ks * 32];
      half8 aH = *(const half8*)&hs[abase + ks * 32];
      int fb = ks * 8;
#pragma unroll
      for (int nt = 0; nt < 8; ++nt) {
        half8 bl = WL[(size_t)(fb + nt) * 64 + lane];
        half8 br = WR[(size_t)(fb + nt) * 64 + lane];
        acc[nt] = __builtin_amdgcn_mfma_f32_16x16x32_f16(aD, bl, acc[nt], 0, 0, 0);
        acc[nt] = __builtin_amdgcn_mfma_f32_16x16x32_f16(aH, br, acc[nt], 0, 0, 0);
      }
    }
    int rb = (lane >> 4) << 2;
    int cl = lane & 15;
#pragma unroll
    for (int nt = 0; nt < 8; ++nt) {
      int col = nt * 16 + cl;
      float bv = bias2[col];
#pragma unroll
      for (int r = 0; r < 4; ++r) {
        float v = fmaxf(acc[nt][r] + bv, 0.f);
        Hs[wid * 16 + rb + r][col] = (half_t)v;
      }
    }
  }
  __syncthreads();

  // ---- phase 2: ns = h2 @ Wout + bout, A from LDS
  if (active) {
    int lrow = wid * 16 + (lane & 15);
    int koff = (lane >> 4) << 3;
    const half8* W8 = (const half8*)wout;
    f32x4 acc2[8];
#pragma unroll
    for (int t = 0; t < 8; ++t) acc2[t] = (f32x4){0.f, 0.f, 0.f, 0.f};
#pragma unroll
    for (int ks = 0; ks < 4; ++ks) {
      half8 aH = *(const half8*)&Hs[lrow][ks * 32 + koff];
      int fb = ks * 8;
#pragma unroll
      for (int nt = 0; nt < 8; ++nt) {
        half8 b = W8[(size_t)(fb + nt) * 64 + lane];
        acc2[nt] = __builtin_amdgcn_mfma_f32_16x16x32_f16(aH, b, acc2[nt], 0, 0, 0);
      }
    }
    int rbase = row0 + ((lane >> 4) << 2);
    int cl = lane & 15;
#pragma unroll
    for (int nt = 0; nt < 8; ++nt) {
      int col = nt * 16 + cl;
      float bv = bout[col];
      float csum = 0.f;
#pragma unroll
      for (int r = 0; r < 4; ++r) {
        int row = rbase + r;
        if (row < n) {
          float v = acc2[nt][r] + bv;
          out[(size_t)row * HID + col] = v;
          csum += v;
        }
      }
      atomicAdd(&colsum[col], csum);
    }
  }
  __syncthreads();
  if (tid < HID) part[(size_t)blockIdx.x * HID + tid] = colsum[tid];
}

// ---------------------------------------------------------------- final column reduce
__global__ __launch_bounds__(256) void k_colfinal(const float* __restrict__ part,
                                                  float* __restrict__ outmean,
                                                  int rows, float inv) {
  __shared__ float red[256];
  int t = threadIdx.x;
  int col = t & 127, half = t >> 7;
  int r0 = blockIdx.x * 256;
  float s = 0.f;
  for (int r = half; r < 256; r += 2) {
    int row = r0 + r;
    if (row < rows) s += part[(size_t)row * HID + col];
  }
  red[t] = s;
  __syncthreads();
  if (t < 128) atomicAdd(&outmean[col], (red[t] + red[t + 128]) * inv);
}

// ---------------------------------------------------------------- launch
extern "C" void kernel_launch(void* const* d_in, const int* in_sizes, int n_in,
                              void* d_out, int out_size, void* d_ws, size_t ws_size,
                              hipStream_t stream) {
  const float* pos  = (const float*)d_in[0];
  const int*   an   = (const int*)d_in[1];
  const int*   ei   = (const int*)d_in[2];
  const float* Win  = (const float*)d_in[3];
  const float* bin  = (const float*)d_in[4];
  const float* W1l  = (const float*)d_in[5];
  const float* b1   = (const float*)d_in[6];
  const float* W1r  = (const float*)d_in[7];
  const float* W2l  = (const float*)d_in[8];
  const float* b2   = (const float*)d_in[9];
  const float* W2r  = (const float*)d_in[10];
  const float* Wout = (const float*)d_in[11];
  const float* bout = (const float*)d_in[12];

  int N = in_sizes[0] / 3;
  int E = in_sizes[2] / 2;
  const int* srcl = ei;
  const int* dstl = ei + E;

  float* outmean = (float*)d_out;
  float* ns      = (float*)d_out + HID;

  char* p = (char*)d_ws;
  auto take = [&](size_t bytes) {
    char* q = p;
    p += (bytes + 255) & ~(size_t)255;
    return q;
  };
  int nbuck = (N + BK_NODES - 1) / BK_NODES;       // 196
  half_t*   H0      = (half_t*)take((size_t)(N + 1) * HID * 2);   // +1 zero row
  half_t*   H1      = (half_t*)take((size_t)(N + 1) * HID * 2);   // +1 zero row
  half_t*   D       = (half_t*)take((size_t)N * HID * 2);
  int*      offs    = (int*)take((size_t)N * 4);
  int*      offsE   = (int*)take((size_t)N * 4);
  int*      csr     = (int*)take((size_t)nbuck * BKCAP * 4);
  unsigned* ebuf    = (unsigned*)take((size_t)nbuck * BKCAP * 4);
  int*      bcur    = (int*)take((size_t)256 * 4);
  half_t*   pW1l    = (half_t*)take((size_t)16384 * 2);
  half_t*   pW1r    = (half_t*)take((size_t)16384 * 2);
  half_t*   pW2l    = (half_t*)take((size_t)16384 * 2);
  half_t*   pW2r    = (half_t*)take((size_t)16384 * 2);
  half_t*   pWout   = (half_t*)take((size_t)16384 * 2);
  int gSage = (N + 63) / 64;
  float*    colpart = (float*)take((size_t)gSage * HID * 4);

  int gEmbed = (int)(((size_t)N * 32 + 255) / 256);
  int gWave  = (N + 3) / 4;
  int gBktA  = (E + EDGES_PER_BLKA - 1) / EDGES_PER_BLKA;

  k_setup<<<gEmbed + 41, 256, 0, stream>>>(pos, an, Win, bin, H0,
                                           W1l, W1r, W2l, W2r, Wout,
                                           pW1l, pW1r, pW2l, pW2r, pWout,
                                           bcur, outmean,
                                           &H0[(size_t)N * HID], &H1[(size_t)N * HID],
                                           N, gEmbed);
  k_bucketA<<<gBktA, 1024, 0, stream>>>(srcl, dstl, bcur, ebuf, E);
  k_bucketB<<<nbuck, 512, 0, stream>>>(ebuf, bcur, offs, offsE, csr, N);

  // conv1
  k_aggmean_f16<<<gWave, 256, 0, stream>>>(H0, csr, offs, offsE, D, N);
  k_sage_mfma<<<gSage, 256, 0, stream>>>(D, H0, pW1l, pW1r, b1, H1, N);
  // conv2 + output projection (fused)
  k_aggmean_f16<<<gWave, 256, 0, stream>>>(H1, csr, offs, offsE, D, N);
  k_sage_out<<<gSage, 256, 0, stream>>>(D, H1, pW2l, pW2r, b2, pWout, bout, ns, colpart, N);
  k_colfinal<<<(gSage + 255) / 256, 256, 0, stream>>>(colpart, outmean, gSage, 1.0f / (float)N);
}